// Round 1
// baseline (578.444 us; speedup 1.0000x reference)
//
#include <hip/hip_runtime.h>
#include <hip/hip_bf16.h>
#include <stdint.h>

#define TT 8192   // tokens
#define HH 1024   // hidden
#define II 2048   // intermediate
#define EE 8      // experts
#define TOPK 2

typedef __bf16 bf16x8 __attribute__((ext_vector_type(8)));
typedef float f32x4 __attribute__((ext_vector_type(4)));

__device__ __forceinline__ unsigned short f2bf(float f) {
  union { float f; unsigned int u; } c; c.f = f;
  unsigned int u = c.u;
  u += 0x7FFFu + ((u >> 16) & 1u);   // RNE
  return (unsigned short)(u >> 16);
}

__device__ __forceinline__ void gload_lds16(const void* g, void* l) {
  __builtin_amdgcn_global_load_lds((const __attribute__((address_space(1))) void*)g,
                                   (__attribute__((address_space(3))) void*)l, 16, 0, 0);
}

// ---------------- x fp32 -> bf16 (layout unchanged, k-contiguous) ----------------
__global__ __launch_bounds__(256) void k_convert_x(const float4* __restrict__ src,
                                                   ushort4* __restrict__ dst, int n4) {
  int i = blockIdx.x * 256 + threadIdx.x;
  if (i >= n4) return;
  float4 v = src[i];
  ushort4 o;
  o.x = f2bf(v.x); o.y = f2bf(v.y); o.z = f2bf(v.z); o.w = f2bf(v.w);
  dst[i] = o;
}

// -------- transpose + convert: src [E][R][C] fp32 -> dst [E][C][R] bf16 --------
__global__ __launch_bounds__(256) void k_transpose_cvt(const float* __restrict__ src,
                                                       unsigned short* __restrict__ dst,
                                                       int R, int C) {
  __shared__ float tile[64][65];
  const float* s = src + (size_t)blockIdx.z * R * C;
  unsigned short* d = dst + (size_t)blockIdx.z * R * C;
  int r0 = blockIdx.y * 64, c0 = blockIdx.x * 64;
  int tx = threadIdx.x & 15;   // 16 float4 per 64-wide row
  int ty = threadIdx.x >> 4;   // 16 rows per pass
#pragma unroll
  for (int i = 0; i < 4; ++i) {
    int rr = i * 16 + ty;
    float4 v = *reinterpret_cast<const float4*>(&s[(size_t)(r0 + rr) * C + c0 + tx * 4]);
    tile[rr][tx * 4 + 0] = v.x; tile[rr][tx * 4 + 1] = v.y;
    tile[rr][tx * 4 + 2] = v.z; tile[rr][tx * 4 + 3] = v.w;
  }
  __syncthreads();
#pragma unroll
  for (int i = 0; i < 4; ++i) {
    int cc = i * 16 + ty;   // dst row = c0+cc
    ushort4 o;
    o.x = f2bf(tile[tx * 4 + 0][cc]);
    o.y = f2bf(tile[tx * 4 + 1][cc]);
    o.z = f2bf(tile[tx * 4 + 2][cc]);
    o.w = f2bf(tile[tx * 4 + 3][cc]);
    *reinterpret_cast<ushort4*>(&d[(size_t)(c0 + cc) * R + r0 + tx * 4]) = o;
  }
}

// ---------------- router: logits, top-2, sigmoid-renorm, expert lists ----------------
__global__ __launch_bounds__(256) void k_router(const float* __restrict__ x,
                                                const float* __restrict__ Wr,
                                                const float* __restrict__ br,
                                                int* __restrict__ tlist,
                                                float* __restrict__ glist,
                                                int* __restrict__ counts) {
  __shared__ float wrt[8][1024];  // Wr transposed, 32 KB
  int tid = threadIdx.x;
  for (int i = tid; i < 8192; i += 256) {
    int h = i >> 3, e = i & 7;
    wrt[e][h] = Wr[i];
  }
  __syncthreads();
  int w = tid >> 6, l = tid & 63;
  int t = blockIdx.x * 4 + w;   // one wave per token
  const float4* xr = reinterpret_cast<const float4*>(x + (size_t)t * HH);
  float acc[8] = {0.f, 0.f, 0.f, 0.f, 0.f, 0.f, 0.f, 0.f};
#pragma unroll
  for (int j = 0; j < 4; ++j) {
    float4 xv = xr[j * 64 + l];
    int hbase = (j * 64 + l) * 4;
#pragma unroll
    for (int e = 0; e < 8; ++e) {
      float4 wv = *reinterpret_cast<const float4*>(&wrt[e][hbase]);
      acc[e] += xv.x * wv.x + xv.y * wv.y + xv.z * wv.z + xv.w * wv.w;
    }
  }
#pragma unroll
  for (int e = 0; e < 8; ++e)
#pragma unroll
    for (int off = 32; off > 0; off >>= 1) acc[e] += __shfl_xor(acc[e], off, 64);
  if (l == 0) {
    float lg[8];
#pragma unroll
    for (int e = 0; e < 8; ++e) lg[e] = acc[e] + br[e];
    int i0 = 0;
#pragma unroll
    for (int e = 1; e < 8; ++e) if (lg[e] > lg[i0]) i0 = e;   // first index on ties
    int i1 = (i0 == 0) ? 1 : 0;
#pragma unroll
    for (int e = 0; e < 8; ++e) if (e != i0 && lg[e] > lg[i1]) i1 = e;
    float g0 = 1.f / (1.f + expf(-lg[i0]));
    float g1 = 1.f / (1.f + expf(-lg[i1]));
    float inv = 1.f / (g0 + g1 + 1e-10f);
    g0 *= inv; g1 *= inv;
    int s0 = atomicAdd(&counts[i0], 1);
    tlist[i0 * TT + s0] = t; glist[i0 * TT + s0] = g0;
    int s1 = atomicAdd(&counts[i1], 1);
    tlist[i1 * TT + s1] = t; glist[i1 * TT + s1] = g1;
  }
}

// ---------------- exclusive prefix over 8 expert counts ----------------
__global__ void k_offsets(const int* __restrict__ counts, int* __restrict__ offs) {
  if (threadIdx.x == 0) {
    int s = 0;
    for (int e = 0; e < EE; ++e) { offs[e] = s; s += counts[e]; }
  }
}

// ---------------- GEMM1: h = silu(x@Wg) * (x@Wu) * gate, grouped by expert --------
// A = gathered x rows (bf16, k-contig), B = WgT/WuT [E][I][H] (k-contig).
// 128x128 tile, BK=64, 4 waves (each 64x64), T2 XOR-swizzled LDS, global_load_lds w16.
__global__ __launch_bounds__(256, 2) void k_gemm1(
    const unsigned short* __restrict__ xb,
    const unsigned short* __restrict__ WgT,
    const unsigned short* __restrict__ WuT,
    const int* __restrict__ tlist, const float* __restrict__ glist,
    const int* __restrict__ counts, const int* __restrict__ offs,
    unsigned short* __restrict__ hbuf) {
  __shared__ unsigned short lsA[128 * 64];
  __shared__ unsigned short lsG[128 * 64];
  __shared__ unsigned short lsU[128 * 64];
  __shared__ int s_tok[128];
  __shared__ float s_gate[128];

  const int e = blockIdx.z;
  const int n_e = counts[e];
  const int row0 = blockIdx.y * 128;
  if (row0 >= n_e) return;                 // uniform early-exit (worst-case grid)
  const int n0 = blockIdx.x * 128;
  const int tid = threadIdx.x;

  if (tid < 128) {
    int r = row0 + tid;
    int tok = 0; float gt = 0.f;
    if (r < n_e) { tok = tlist[e * TT + r]; gt = glist[e * TT + r]; }
    s_tok[tid] = tok; s_gate[tid] = gt;
  }
  __syncthreads();

  // staging: linear LDS dest, inverse-swizzled global source (G21: both-sides)
  const int scol = (tid & 7) ^ ((tid >> 3) & 7);
  const unsigned short* srcA[4];
  const unsigned short* srcG[4];
  const unsigned short* srcU[4];
#pragma unroll
  for (int i = 0; i < 4; ++i) {
    int row = i * 32 + (tid >> 3);
    srcA[i] = xb + (size_t)s_tok[row] * HH + scol * 8;
    size_t wrow = ((size_t)e * II + n0 + row) * HH + scol * 8;
    srcG[i] = WgT + wrow;
    srcU[i] = WuT + wrow;
  }

  f32x4 zero = {0.f, 0.f, 0.f, 0.f};
  f32x4 accg[4][4], accu[4][4];
#pragma unroll
  for (int m = 0; m < 4; ++m)
#pragma unroll
    for (int n = 0; n < 4; ++n) { accg[m][n] = zero; accu[m][n] = zero; }

  const int l = tid & 63;
  const int w = tid >> 6;
  const int wr = (w >> 1) * 64;
  const int wc = (w & 1) * 64;
  const int lrow = l & 15;
  const int lk = l >> 4;
  const int swz = (l & 7) << 4;
  const int aoff0 = (wr + lrow) * 128 + lk * 16;
  const int boff0 = (wc + lrow) * 128 + lk * 16;
  const char* lcA = (const char*)lsA;
  const char* lcG = (const char*)lsG;
  const char* lcU = (const char*)lsU;

  for (int kt = 0; kt < HH / 64; ++kt) {
#pragma unroll
    for (int i = 0; i < 4; ++i) {
      gload_lds16(srcA[i] + kt * 64, (char*)lsA + i * 4096 + tid * 16);
      gload_lds16(srcG[i] + kt * 64, (char*)lsG + i * 4096 + tid * 16);
      gload_lds16(srcU[i] + kt * 64, (char*)lsU + i * 4096 + tid * 16);
    }
    __syncthreads();
#pragma unroll
    for (int kk = 0; kk < 2; ++kk) {
      bf16x8 af[4], bg[4], bu[4];
#pragma unroll
      for (int m = 0; m < 4; ++m)
        af[m] = *(const bf16x8*)(lcA + ((aoff0 + m * 2048 + kk * 64) ^ swz));
#pragma unroll
      for (int n = 0; n < 4; ++n) {
        bg[n] = *(const bf16x8*)(lcG + ((boff0 + n * 2048 + kk * 64) ^ swz));
        bu[n] = *(const bf16x8*)(lcU + ((boff0 + n * 2048 + kk * 64) ^ swz));
      }
#pragma unroll
      for (int m = 0; m < 4; ++m)
#pragma unroll
        for (int n = 0; n < 4; ++n) {
          accg[m][n] = __builtin_amdgcn_mfma_f32_16x16x32_bf16(af[m], bg[n], accg[m][n], 0, 0, 0);
          accu[m][n] = __builtin_amdgcn_mfma_f32_16x16x32_bf16(af[m], bu[n], accu[m][n], 0, 0, 0);
        }
    }
    __syncthreads();
  }

  const int obase = offs[e];
#pragma unroll
  for (int m = 0; m < 4; ++m)
#pragma unroll
    for (int n = 0; n < 4; ++n)
#pragma unroll
      for (int r = 0; r < 4; ++r) {
        int rl = wr + m * 16 + lk * 4 + r;   // C/D: col=lane&15, row=(lane>>4)*4+reg
        if (row0 + rl < n_e) {
          float gv = accg[m][n][r];
          float uv = accu[m][n][r];
          float val = gv / (1.f + __expf(-gv)) * uv * s_gate[rl];
          hbuf[(size_t)(obase + row0 + rl) * II + n0 + wc + n * 16 + lrow] = f2bf(val);
        }
      }
}

// ---------------- GEMM2: out += h @ Wd (grouped, scatter-add via HW f32 atomics) ----
__global__ __launch_bounds__(256, 2) void k_gemm2(
    const unsigned short* __restrict__ hbuf,
    const unsigned short* __restrict__ WdT,   // [E][H][I] (k=I contiguous)
    const int* __restrict__ tlist,
    const int* __restrict__ counts, const int* __restrict__ offs,
    float* __restrict__ out) {
  __shared__ unsigned short lsA[128 * 64];
  __shared__ unsigned short lsB[128 * 64];
  __shared__ int s_tok[128];

  const int e = blockIdx.z;
  const int n_e = counts[e];
  const int row0 = blockIdx.y * 128;
  if (row0 >= n_e) return;
  const int n0 = blockIdx.x * 128;   // H columns
  const int tid = threadIdx.x;
  const int obase = offs[e];

  if (tid < 128) {
    int r = row0 + tid;
    s_tok[tid] = (r < n_e) ? tlist[e * TT + r] : 0;
  }
  __syncthreads();

  const int scol = (tid & 7) ^ ((tid >> 3) & 7);
  const unsigned short* srcA[4];
  const unsigned short* srcB[4];
#pragma unroll
  for (int i = 0; i < 4; ++i) {
    int row = i * 32 + (tid >> 3);
    int ar = obase + row0 + row;
    if (ar > TT * TOPK - 1) ar = TT * TOPK - 1;   // clamp pad rows inside hbuf
    srcA[i] = hbuf + (size_t)ar * II + scol * 8;
    srcB[i] = WdT + ((size_t)e * HH + n0 + row) * II + scol * 8;
  }

  f32x4 zero = {0.f, 0.f, 0.f, 0.f};
  f32x4 acc[4][4];
#pragma unroll
  for (int m = 0; m < 4; ++m)
#pragma unroll
    for (int n = 0; n < 4; ++n) acc[m][n] = zero;

  const int l = tid & 63;
  const int w = tid >> 6;
  const int wr = (w >> 1) * 64;
  const int wc = (w & 1) * 64;
  const int lrow = l & 15;
  const int lk = l >> 4;
  const int swz = (l & 7) << 4;
  const int aoff0 = (wr + lrow) * 128 + lk * 16;
  const int boff0 = (wc + lrow) * 128 + lk * 16;
  const char* lcA = (const char*)lsA;
  const char* lcB = (const char*)lsB;

  for (int kt = 0; kt < II / 64; ++kt) {
#pragma unroll
    for (int i = 0; i < 4; ++i) {
      gload_lds16(srcA[i] + kt * 64, (char*)lsA + i * 4096 + tid * 16);
      gload_lds16(srcB[i] + kt * 64, (char*)lsB + i * 4096 + tid * 16);
    }
    __syncthreads();
#pragma unroll
    for (int kk = 0; kk < 2; ++kk) {
      bf16x8 af[4], bf[4];
#pragma unroll
      for (int m = 0; m < 4; ++m)
        af[m] = *(const bf16x8*)(lcA + ((aoff0 + m * 2048 + kk * 64) ^ swz));
#pragma unroll
      for (int n = 0; n < 4; ++n)
        bf[n] = *(const bf16x8*)(lcB + ((boff0 + n * 2048 + kk * 64) ^ swz));
#pragma unroll
      for (int m = 0; m < 4; ++m)
#pragma unroll
        for (int n = 0; n < 4; ++n)
          acc[m][n] = __builtin_amdgcn_mfma_f32_16x16x32_bf16(af[m], bf[n], acc[m][n], 0, 0, 0);
    }
    __syncthreads();
  }

#pragma unroll
  for (int m = 0; m < 4; ++m)
#pragma unroll
    for (int n = 0; n < 4; ++n)
#pragma unroll
      for (int r = 0; r < 4; ++r) {
        int rl = wr + m * 16 + lk * 4 + r;
        if (row0 + rl < n_e) {
          int t = s_tok[rl];
          unsafeAtomicAdd(&out[(size_t)t * HH + n0 + wc + n * 16 + lrow], acc[m][n][r]);
        }
      }
}

extern "C" void kernel_launch(void* const* d_in, const int* in_sizes, int n_in,
                              void* d_out, int out_size, void* d_ws, size_t ws_size,
                              hipStream_t stream) {
  const float* x  = (const float*)d_in[0];
  const float* Wr = (const float*)d_in[1];
  const float* br = (const float*)d_in[2];
  const float* Wg = (const float*)d_in[3];
  const float* Wu = (const float*)d_in[4];
  const float* Wd = (const float*)d_in[5];
  float* out = (float*)d_out;

  char* ws = (char*)d_ws;
  size_t off = 0;
  auto alloc = [&](size_t bytes) {
    char* p = ws + off;
    off += (bytes + 255) & ~(size_t)255;
    return p;
  };
  unsigned short* xb   = (unsigned short*)alloc((size_t)TT * HH * 2);        // 16 MB
  unsigned short* WgT  = (unsigned short*)alloc((size_t)EE * HH * II * 2);   // 32 MB
  unsigned short* WuT  = (unsigned short*)alloc((size_t)EE * HH * II * 2);   // 32 MB
  unsigned short* WdT  = (unsigned short*)alloc((size_t)EE * HH * II * 2);   // 32 MB
  unsigned short* hbuf = (unsigned short*)alloc((size_t)TT * TOPK * II * 2); // 64 MB
  int*   tlist  = (int*)alloc((size_t)EE * TT * 4);
  float* glist  = (float*)alloc((size_t)EE * TT * 4);
  int*   counts = (int*)alloc(128);
  int*   offs   = (int*)alloc(128);

  hipMemsetAsync(counts, 0, 128, stream);
  hipMemsetAsync(d_out, 0, (size_t)TT * HH * 4, stream);

  k_convert_x<<<(TT * HH / 4 + 255) / 256, 256, 0, stream>>>(
      (const float4*)x, (ushort4*)xb, TT * HH / 4);

  dim3 tg1(II / 64, HH / 64, EE);   // Wg/Wu: [H][I] -> [I][H]
  k_transpose_cvt<<<tg1, 256, 0, stream>>>(Wg, WgT, HH, II);
  k_transpose_cvt<<<tg1, 256, 0, stream>>>(Wu, WuT, HH, II);
  dim3 tg2(HH / 64, II / 64, EE);   // Wd: [I][H] -> [H][I]
  k_transpose_cvt<<<tg2, 256, 0, stream>>>(Wd, WdT, II, HH);

  k_router<<<TT / 4, 256, 0, stream>>>(x, Wr, br, tlist, glist, counts);
  k_offsets<<<1, 64, 0, stream>>>(counts, offs);

  dim3 g1(II / 128, TT / 128, EE);
  k_gemm1<<<g1, 256, 0, stream>>>(xb, WgT, WuT, tlist, glist, counts, offs, hbuf);
  dim3 g2(HH / 128, TT / 128, EE);
  k_gemm2<<<g2, 256, 0, stream>>>(hbuf, WdT, tlist, counts, offs, out);

  (void)in_sizes; (void)n_in; (void)out_size; (void)ws_size;
}

// Round 2
// 430.802 us; speedup vs baseline: 1.3427x; 1.3427x over previous
//
#include <hip/hip_runtime.h>
#include <hip/hip_bf16.h>
#include <stdint.h>

#define TT 8192   // tokens
#define HH 1024   // hidden
#define II 2048   // intermediate
#define EE 8      // experts
#define TOPK 2

typedef __bf16 bf16x8 __attribute__((ext_vector_type(8)));
typedef float f32x4 __attribute__((ext_vector_type(4)));

__device__ __forceinline__ unsigned short f2bf(float f) {
  union { float f; unsigned int u; } c; c.f = f;
  unsigned int u = c.u;
  u += 0x7FFFu + ((u >> 16) & 1u);   // RNE
  return (unsigned short)(u >> 16);
}

__device__ __forceinline__ void gload_lds16(const void* g, void* l) {
  __builtin_amdgcn_global_load_lds((const __attribute__((address_space(1))) void*)g,
                                   (__attribute__((address_space(3))) void*)l, 16, 0, 0);
}

// ---------------- x fp32 -> bf16 (layout unchanged, k-contiguous) ----------------
__global__ __launch_bounds__(256) void k_convert_x(const float4* __restrict__ src,
                                                   ushort4* __restrict__ dst, int n4) {
  int i = blockIdx.x * 256 + threadIdx.x;
  if (i >= n4) return;
  float4 v = src[i];
  ushort4 o;
  o.x = f2bf(v.x); o.y = f2bf(v.y); o.z = f2bf(v.z); o.w = f2bf(v.w);
  dst[i] = o;
}

// -------- transpose + convert: src [E][R][C] fp32 -> dst [E][C][R] bf16 --------
__global__ __launch_bounds__(256) void k_transpose_cvt(const float* __restrict__ src,
                                                       unsigned short* __restrict__ dst,
                                                       int R, int C) {
  __shared__ float tile[64][65];
  const float* s = src + (size_t)blockIdx.z * R * C;
  unsigned short* d = dst + (size_t)blockIdx.z * R * C;
  int r0 = blockIdx.y * 64, c0 = blockIdx.x * 64;
  int tx = threadIdx.x & 15;   // 16 float4 per 64-wide row
  int ty = threadIdx.x >> 4;   // 16 rows per pass
#pragma unroll
  for (int i = 0; i < 4; ++i) {
    int rr = i * 16 + ty;
    float4 v = *reinterpret_cast<const float4*>(&s[(size_t)(r0 + rr) * C + c0 + tx * 4]);
    tile[rr][tx * 4 + 0] = v.x; tile[rr][tx * 4 + 1] = v.y;
    tile[rr][tx * 4 + 2] = v.z; tile[rr][tx * 4 + 3] = v.w;
  }
  __syncthreads();
#pragma unroll
  for (int i = 0; i < 4; ++i) {
    int cc = i * 16 + ty;   // dst row = c0+cc
    ushort4 o;
    o.x = f2bf(tile[tx * 4 + 0][cc]);
    o.y = f2bf(tile[tx * 4 + 1][cc]);
    o.z = f2bf(tile[tx * 4 + 2][cc]);
    o.w = f2bf(tile[tx * 4 + 3][cc]);
    *reinterpret_cast<ushort4*>(&d[(size_t)(c0 + cc) * R + r0 + tx * 4]) = o;
  }
}

// ---------------- router: logits, top-2, sigmoid-renorm, expert lists ----------------
// 128 blocks x 64 tokens. Slot claims via LDS atomics; ONE aggregated global
// atomicAdd per expert per block (8/block, 1024 total) instead of 2 per token
// (16384 same-line serialized atomics == the old 195 us).
__global__ __launch_bounds__(256) void k_router(const float* __restrict__ x,
                                                const float* __restrict__ Wr,
                                                const float* __restrict__ br,
                                                int* __restrict__ tlist,
                                                float* __restrict__ glist,
                                                int* __restrict__ counts) {
  __shared__ float wrt[8][1024];  // Wr transposed, 32 KB
  __shared__ int lcount[8];
  __shared__ int lbase[8];
  __shared__ short ent_e[128];    // 64 tokens * 2 entries
  __shared__ short ent_slot[128];
  __shared__ float ent_g[128];
  int tid = threadIdx.x;
  for (int i = tid; i < 8192; i += 256) {
    wrt[i & 7][i >> 3] = Wr[i];
  }
  if (tid < 8) lcount[tid] = 0;
  __syncthreads();
  int w = tid >> 6, l = tid & 63;
  int t0 = blockIdx.x * 64;
  for (int it = 0; it < 16; ++it) {
    int t = t0 + w * 16 + it;   // one wave per token per iteration
    const float4* xr = reinterpret_cast<const float4*>(x + (size_t)t * HH);
    float acc[8] = {0.f, 0.f, 0.f, 0.f, 0.f, 0.f, 0.f, 0.f};
#pragma unroll
    for (int j = 0; j < 4; ++j) {
      float4 xv = xr[j * 64 + l];
      int hbase = (j * 64 + l) * 4;
#pragma unroll
      for (int e = 0; e < 8; ++e) {
        float4 wv = *reinterpret_cast<const float4*>(&wrt[e][hbase]);
        acc[e] += xv.x * wv.x + xv.y * wv.y + xv.z * wv.z + xv.w * wv.w;
      }
    }
#pragma unroll
    for (int e = 0; e < 8; ++e)
#pragma unroll
      for (int off = 32; off > 0; off >>= 1) acc[e] += __shfl_xor(acc[e], off, 64);
    if (l == 0) {
      float lg[8];
#pragma unroll
      for (int e = 0; e < 8; ++e) lg[e] = acc[e] + br[e];
      int i0 = 0;
#pragma unroll
      for (int e = 1; e < 8; ++e) if (lg[e] > lg[i0]) i0 = e;   // first index on ties
      int i1 = (i0 == 0) ? 1 : 0;
#pragma unroll
      for (int e = 0; e < 8; ++e) if (e != i0 && lg[e] > lg[i1]) i1 = e;
      float g0 = 1.f / (1.f + expf(-lg[i0]));
      float g1 = 1.f / (1.f + expf(-lg[i1]));
      float inv = 1.f / (g0 + g1 + 1e-10f);
      int idx = (w * 16 + it) * 2;
      int s0 = atomicAdd(&lcount[i0], 1);   // LDS atomic: fast, per-CU
      ent_e[idx] = (short)i0; ent_slot[idx] = (short)s0; ent_g[idx] = g0 * inv;
      int s1 = atomicAdd(&lcount[i1], 1);
      ent_e[idx + 1] = (short)i1; ent_slot[idx + 1] = (short)s1; ent_g[idx + 1] = g1 * inv;
    }
  }
  __syncthreads();
  if (tid < 8) lbase[tid] = atomicAdd(&counts[tid], lcount[tid]);  // 8 global atomics/block
  __syncthreads();
  if (tid < 128) {
    int e = ent_e[tid];
    int slot = lbase[e] + ent_slot[tid];
    int t = t0 + (tid >> 1);
    tlist[e * TT + slot] = t;
    glist[e * TT + slot] = ent_g[tid];
  }
}

// ---------------- exclusive prefix over 8 expert counts ----------------
__global__ void k_offsets(const int* __restrict__ counts, int* __restrict__ offs) {
  if (threadIdx.x == 0) {
    int s = 0;
    for (int e = 0; e < EE; ++e) { offs[e] = s; s += counts[e]; }
  }
}

// ---------------- GEMM1: h = silu(x@Wg) * (x@Wu) * gate, grouped by expert --------
// A = gathered x rows (bf16, k-contig), B = WgT/WuT [E][I][H] (k-contig).
// 128x128 tile, BK=64, 4 waves (each 64x64), T2 XOR-swizzled LDS, global_load_lds w16.
__global__ __launch_bounds__(256, 2) void k_gemm1(
    const unsigned short* __restrict__ xb,
    const unsigned short* __restrict__ WgT,
    const unsigned short* __restrict__ WuT,
    const int* __restrict__ tlist, const float* __restrict__ glist,
    const int* __restrict__ counts, const int* __restrict__ offs,
    unsigned short* __restrict__ hbuf) {
  __shared__ unsigned short lsA[128 * 64];
  __shared__ unsigned short lsG[128 * 64];
  __shared__ unsigned short lsU[128 * 64];
  __shared__ int s_tok[128];
  __shared__ float s_gate[128];

  const int e = blockIdx.z;
  const int n_e = counts[e];
  const int row0 = blockIdx.y * 128;
  if (row0 >= n_e) return;                 // uniform early-exit (worst-case grid)
  const int n0 = blockIdx.x * 128;
  const int tid = threadIdx.x;

  if (tid < 128) {
    int r = row0 + tid;
    int tok = 0; float gt = 0.f;
    if (r < n_e) { tok = tlist[e * TT + r]; gt = glist[e * TT + r]; }
    s_tok[tid] = tok; s_gate[tid] = gt;
  }
  __syncthreads();

  // staging: linear LDS dest, inverse-swizzled global source (G21: both-sides)
  const int scol = (tid & 7) ^ ((tid >> 3) & 7);
  const unsigned short* srcA[4];
  const unsigned short* srcG[4];
  const unsigned short* srcU[4];
#pragma unroll
  for (int i = 0; i < 4; ++i) {
    int row = i * 32 + (tid >> 3);
    srcA[i] = xb + (size_t)s_tok[row] * HH + scol * 8;
    size_t wrow = ((size_t)e * II + n0 + row) * HH + scol * 8;
    srcG[i] = WgT + wrow;
    srcU[i] = WuT + wrow;
  }

  f32x4 zero = {0.f, 0.f, 0.f, 0.f};
  f32x4 accg[4][4], accu[4][4];
#pragma unroll
  for (int m = 0; m < 4; ++m)
#pragma unroll
    for (int n = 0; n < 4; ++n) { accg[m][n] = zero; accu[m][n] = zero; }

  const int l = tid & 63;
  const int w = tid >> 6;
  const int wr = (w >> 1) * 64;
  const int wc = (w & 1) * 64;
  const int lrow = l & 15;
  const int lk = l >> 4;
  const int swz = (l & 7) << 4;
  const int aoff0 = (wr + lrow) * 128 + lk * 16;
  const int boff0 = (wc + lrow) * 128 + lk * 16;
  const char* lcA = (const char*)lsA;
  const char* lcG = (const char*)lsG;
  const char* lcU = (const char*)lsU;

  for (int kt = 0; kt < HH / 64; ++kt) {
#pragma unroll
    for (int i = 0; i < 4; ++i) {
      gload_lds16(srcA[i] + kt * 64, (char*)lsA + i * 4096 + tid * 16);
      gload_lds16(srcG[i] + kt * 64, (char*)lsG + i * 4096 + tid * 16);
      gload_lds16(srcU[i] + kt * 64, (char*)lsU + i * 4096 + tid * 16);
    }
    __syncthreads();
#pragma unroll
    for (int kk = 0; kk < 2; ++kk) {
      bf16x8 af[4], bg[4], bu[4];
#pragma unroll
      for (int m = 0; m < 4; ++m)
        af[m] = *(const bf16x8*)(lcA + ((aoff0 + m * 2048 + kk * 64) ^ swz));
#pragma unroll
      for (int n = 0; n < 4; ++n) {
        bg[n] = *(const bf16x8*)(lcG + ((boff0 + n * 2048 + kk * 64) ^ swz));
        bu[n] = *(const bf16x8*)(lcU + ((boff0 + n * 2048 + kk * 64) ^ swz));
      }
#pragma unroll
      for (int m = 0; m < 4; ++m)
#pragma unroll
        for (int n = 0; n < 4; ++n) {
          accg[m][n] = __builtin_amdgcn_mfma_f32_16x16x32_bf16(af[m], bg[n], accg[m][n], 0, 0, 0);
          accu[m][n] = __builtin_amdgcn_mfma_f32_16x16x32_bf16(af[m], bu[n], accu[m][n], 0, 0, 0);
        }
    }
    __syncthreads();
  }

  const int obase = offs[e];
#pragma unroll
  for (int m = 0; m < 4; ++m)
#pragma unroll
    for (int n = 0; n < 4; ++n)
#pragma unroll
      for (int r = 0; r < 4; ++r) {
        int rl = wr + m * 16 + lk * 4 + r;   // C/D: col=lane&15, row=(lane>>4)*4+reg
        if (row0 + rl < n_e) {
          float gv = accg[m][n][r];
          float uv = accu[m][n][r];
          float val = gv / (1.f + __expf(-gv)) * uv * s_gate[rl];
          hbuf[(size_t)(obase + row0 + rl) * II + n0 + wc + n * 16 + lrow] = f2bf(val);
        }
      }
}

// ---------------- GEMM2: out += h @ Wd (grouped, scatter-add via HW f32 atomics) ----
__global__ __launch_bounds__(256, 2) void k_gemm2(
    const unsigned short* __restrict__ hbuf,
    const unsigned short* __restrict__ WdT,   // [E][H][I] (k=I contiguous)
    const int* __restrict__ tlist,
    const int* __restrict__ counts, const int* __restrict__ offs,
    float* __restrict__ out) {
  __shared__ unsigned short lsA[128 * 64];
  __shared__ unsigned short lsB[128 * 64];
  __shared__ int s_tok[128];

  const int e = blockIdx.z;
  const int n_e = counts[e];
  const int row0 = blockIdx.y * 128;
  if (row0 >= n_e) return;
  const int n0 = blockIdx.x * 128;   // H columns
  const int tid = threadIdx.x;
  const int obase = offs[e];

  if (tid < 128) {
    int r = row0 + tid;
    s_tok[tid] = (r < n_e) ? tlist[e * TT + r] : 0;
  }
  __syncthreads();

  const int scol = (tid & 7) ^ ((tid >> 3) & 7);
  const unsigned short* srcA[4];
  const unsigned short* srcB[4];
#pragma unroll
  for (int i = 0; i < 4; ++i) {
    int row = i * 32 + (tid >> 3);
    int ar = obase + row0 + row;
    if (ar > TT * TOPK - 1) ar = TT * TOPK - 1;   // clamp pad rows inside hbuf
    srcA[i] = hbuf + (size_t)ar * II + scol * 8;
    srcB[i] = WdT + ((size_t)e * HH + n0 + row) * II + scol * 8;
  }

  f32x4 zero = {0.f, 0.f, 0.f, 0.f};
  f32x4 acc[4][4];
#pragma unroll
  for (int m = 0; m < 4; ++m)
#pragma unroll
    for (int n = 0; n < 4; ++n) acc[m][n] = zero;

  const int l = tid & 63;
  const int w = tid >> 6;
  const int wr = (w >> 1) * 64;
  const int wc = (w & 1) * 64;
  const int lrow = l & 15;
  const int lk = l >> 4;
  const int swz = (l & 7) << 4;
  const int aoff0 = (wr + lrow) * 128 + lk * 16;
  const int boff0 = (wc + lrow) * 128 + lk * 16;
  const char* lcA = (const char*)lsA;
  const char* lcB = (const char*)lsB;

  for (int kt = 0; kt < II / 64; ++kt) {
#pragma unroll
    for (int i = 0; i < 4; ++i) {
      gload_lds16(srcA[i] + kt * 64, (char*)lsA + i * 4096 + tid * 16);
      gload_lds16(srcB[i] + kt * 64, (char*)lsB + i * 4096 + tid * 16);
    }
    __syncthreads();
#pragma unroll
    for (int kk = 0; kk < 2; ++kk) {
      bf16x8 af[4], bf[4];
#pragma unroll
      for (int m = 0; m < 4; ++m)
        af[m] = *(const bf16x8*)(lcA + ((aoff0 + m * 2048 + kk * 64) ^ swz));
#pragma unroll
      for (int n = 0; n < 4; ++n)
        bf[n] = *(const bf16x8*)(lcB + ((boff0 + n * 2048 + kk * 64) ^ swz));
#pragma unroll
      for (int m = 0; m < 4; ++m)
#pragma unroll
        for (int n = 0; n < 4; ++n)
          acc[m][n] = __builtin_amdgcn_mfma_f32_16x16x32_bf16(af[m], bf[n], acc[m][n], 0, 0, 0);
    }
    __syncthreads();
  }

#pragma unroll
  for (int m = 0; m < 4; ++m)
#pragma unroll
    for (int n = 0; n < 4; ++n)
#pragma unroll
      for (int r = 0; r < 4; ++r) {
        int rl = wr + m * 16 + lk * 4 + r;
        if (row0 + rl < n_e) {
          int t = s_tok[rl];
          unsafeAtomicAdd(&out[(size_t)t * HH + n0 + wc + n * 16 + lrow], acc[m][n][r]);
        }
      }
}

extern "C" void kernel_launch(void* const* d_in, const int* in_sizes, int n_in,
                              void* d_out, int out_size, void* d_ws, size_t ws_size,
                              hipStream_t stream) {
  const float* x  = (const float*)d_in[0];
  const float* Wr = (const float*)d_in[1];
  const float* br = (const float*)d_in[2];
  const float* Wg = (const float*)d_in[3];
  const float* Wu = (const float*)d_in[4];
  const float* Wd = (const float*)d_in[5];
  float* out = (float*)d_out;

  char* ws = (char*)d_ws;
  size_t off = 0;
  auto alloc = [&](size_t bytes) {
    char* p = ws + off;
    off += (bytes + 255) & ~(size_t)255;
    return p;
  };
  unsigned short* xb   = (unsigned short*)alloc((size_t)TT * HH * 2);        // 16 MB
  unsigned short* WgT  = (unsigned short*)alloc((size_t)EE * HH * II * 2);   // 32 MB
  unsigned short* WuT  = (unsigned short*)alloc((size_t)EE * HH * II * 2);   // 32 MB
  unsigned short* WdT  = (unsigned short*)alloc((size_t)EE * HH * II * 2);   // 32 MB
  unsigned short* hbuf = (unsigned short*)alloc((size_t)TT * TOPK * II * 2); // 64 MB
  int*   tlist  = (int*)alloc((size_t)EE * TT * 4);
  float* glist  = (float*)alloc((size_t)EE * TT * 4);
  int*   counts = (int*)alloc(128);
  int*   offs   = (int*)alloc(128);

  hipMemsetAsync(counts, 0, 128, stream);
  hipMemsetAsync(d_out, 0, (size_t)TT * HH * 4, stream);

  k_convert_x<<<(TT * HH / 4 + 255) / 256, 256, 0, stream>>>(
      (const float4*)x, (ushort4*)xb, TT * HH / 4);

  dim3 tg1(II / 64, HH / 64, EE);   // Wg/Wu: [H][I] -> [I][H]
  k_transpose_cvt<<<tg1, 256, 0, stream>>>(Wg, WgT, HH, II);
  k_transpose_cvt<<<tg1, 256, 0, stream>>>(Wu, WuT, HH, II);
  dim3 tg2(HH / 64, II / 64, EE);   // Wd: [I][H] -> [H][I]
  k_transpose_cvt<<<tg2, 256, 0, stream>>>(Wd, WdT, II, HH);

  k_router<<<TT / 64, 256, 0, stream>>>(x, Wr, br, tlist, glist, counts);
  k_offsets<<<1, 64, 0, stream>>>(counts, offs);

  dim3 g1(II / 128, TT / 128, EE);
  k_gemm1<<<g1, 256, 0, stream>>>(xb, WgT, WuT, tlist, glist, counts, offs, hbuf);
  dim3 g2(HH / 128, TT / 128, EE);
  k_gemm2<<<g2, 256, 0, stream>>>(hbuf, WdT, tlist, counts, offs, out);

  (void)in_sizes; (void)n_in; (void)out_size; (void)ws_size;
}